// Round 9
// baseline (115.485 us; speedup 1.0000x reference)
//
#include <hip/hip_runtime.h>
#include <math.h>

#define T_LEN  65536
#define T_PAD  65792      // T + STEP
#define C_CH   64
#define STEP_  256
#define K_     257        // WS/2 + 1
#define NW     16         // waves per block
#define NIT    16         // iterations (NW frames each)

// XOR-swizzle: fold float2-index bits[5:4] into bank bits[3:2].
#define SW(i) ((i) ^ (((i) >> 2) & 12))

#define CFENCE() asm volatile("" ::: "memory")
// barrier that does NOT drain vmcnt: prefetch loads stay in flight
#define BAR() do { asm volatile("s_waitcnt lgkmcnt(0)" ::: "memory"); \
                   __builtin_amdgcn_s_barrier(); \
                   asm volatile("" ::: "memory"); } while (0)

__device__ __forceinline__ float2 cadd(float2 a, float2 b) { return make_float2(a.x + b.x, a.y + b.y); }
__device__ __forceinline__ float2 csub(float2 a, float2 b) { return make_float2(a.x - b.x, a.y - b.y); }
__device__ __forceinline__ float2 cmul(float2 a, float2 b) {
    return make_float2(a.x * b.x - a.y * b.y, a.x * b.y + a.y * b.x);
}
template <int SGN>
__device__ __forceinline__ float2 cmulsg(float2 w, float2 t) {
    if (SGN > 0) return make_float2(w.x * t.x - w.y * t.y, w.x * t.y + w.y * t.x);
    else         return make_float2(w.x * t.x + w.y * t.y, w.x * t.y - w.y * t.x);
}
template <int SGN>
__device__ __forceinline__ void bfly4(float2 z0, float2 z1, float2 z2, float2 z3,
                                      float2& o0, float2& o1, float2& o2, float2& o3,
                                      float2 w1, float2 w2, float2 w3) {
    float2 apc = cadd(z0, z2), amc = csub(z0, z2);
    float2 bpd = cadd(z1, z3), bmd = csub(z1, z3);
    float2 jb  = make_float2(-bmd.y, bmd.x);
    float2 t1, t3;
    if (SGN > 0) { t1 = csub(amc, jb); t3 = cadd(amc, jb); }
    else         { t1 = cadd(amc, jb); t3 = csub(amc, jb); }
    o0 = cadd(apc, bpd);
    o1 = cmulsg<SGN>(w1, t1);
    o2 = cmulsg<SGN>(w2, csub(apc, bpd));
    o3 = cmulsg<SGN>(w3, t3);
}
template <int SGN>
__device__ __forceinline__ void bfly4nt(float2 z0, float2 z1, float2 z2, float2 z3,
                                        float2& o0, float2& o1, float2& o2, float2& o3) {
    float2 apc = cadd(z0, z2), amc = csub(z0, z2);
    float2 bpd = cadd(z1, z3), bmd = csub(z1, z3);
    float2 jb  = make_float2(-bmd.y, bmd.x);
    o0 = cadd(apc, bpd);
    o2 = csub(apc, bpd);
    if (SGN > 0) { o1 = csub(amc, jb); o3 = cadd(amc, jb); }
    else         { o1 = cadd(amc, jb); o3 = csub(amc, jb); }
}

__device__ __forceinline__ float ftanh(float x) {
    float e = __expf(2.0f * x);
    return 1.0f - 2.0f * __builtin_amdgcn_rcpf(e + 1.0f);
}

// ---------------- kernel 1: channel mix + zero pad -------------------------
__global__ __launch_bounds__(512, 1) void mix_kernel(const float* __restrict__ x,
                                                     const float* __restrict__ mixer,
                                                     float* __restrict__ mixed) {
    __shared__ __align__(16) float xt[64][128];
    __shared__ __align__(16) float mx[64][64];
    int tid = threadIdx.x;
    int b   = blockIdx.y;
    int t0  = blockIdx.x * 128;

    if (t0 >= T_LEN) {   // zero-pad region [T, T_PAD)
        for (int f = tid; f < 8192; f += 512) {
            int d = f >> 7, tt = f & 127;
            mixed[((size_t)(b * C_CH + d)) * T_PAD + t0 + tt] = 0.0f;
        }
        return;
    }
    for (int f = tid; f < 4096; f += 512) reinterpret_cast<float*>(mx)[f] = mixer[f];
    for (int f4 = tid; f4 < 2048; f4 += 512) {
        int cc = f4 >> 5, tt4 = f4 & 31;
        *reinterpret_cast<float4*>(&xt[cc][tt4 * 4]) =
            *reinterpret_cast<const float4*>(&x[((size_t)(b * C_CH + cc)) * T_LEN + t0 + tt4 * 4]);
    }
    __syncthreads();

    int tp = tid & 63, grp = tid >> 6;
    int dbase = grp * 8;
    float2 acc[8];
#pragma unroll
    for (int i = 0; i < 8; ++i) acc[i] = make_float2(0.0f, 0.0f);
    for (int cc = 0; cc < 64; ++cc) {
        float2 xv = *reinterpret_cast<const float2*>(&xt[cc][2 * tp]);
        float4 m0 = *reinterpret_cast<const float4*>(&mx[cc][dbase + 0]);
        float4 m1 = *reinterpret_cast<const float4*>(&mx[cc][dbase + 4]);
        acc[0].x = fmaf(xv.x, m0.x, acc[0].x); acc[0].y = fmaf(xv.y, m0.x, acc[0].y);
        acc[1].x = fmaf(xv.x, m0.y, acc[1].x); acc[1].y = fmaf(xv.y, m0.y, acc[1].y);
        acc[2].x = fmaf(xv.x, m0.z, acc[2].x); acc[2].y = fmaf(xv.y, m0.z, acc[2].y);
        acc[3].x = fmaf(xv.x, m0.w, acc[3].x); acc[3].y = fmaf(xv.y, m0.w, acc[3].y);
        acc[4].x = fmaf(xv.x, m1.x, acc[4].x); acc[4].y = fmaf(xv.y, m1.x, acc[4].y);
        acc[5].x = fmaf(xv.x, m1.y, acc[5].x); acc[5].y = fmaf(xv.y, m1.y, acc[5].y);
        acc[6].x = fmaf(xv.x, m1.z, acc[6].x); acc[6].y = fmaf(xv.y, m1.z, acc[6].y);
        acc[7].x = fmaf(xv.x, m1.w, acc[7].x); acc[7].y = fmaf(xv.y, m1.w, acc[7].y);
    }
#pragma unroll
    for (int i = 0; i < 8; ++i)
        *reinterpret_cast<float2*>(&mixed[((size_t)(b * C_CH + dbase + i)) * T_PAD + t0 + 2 * tp]) = acc[i];
}

// -------- kernel 2: fused STFT -> scan -> iSTFT -> window -> OLA -> tanh ---
// ONE barrier per iteration: phase2 = scan(it) || inverse(it-1) || store(it-2).
// olab2 double-buffered by parity; tails 4-deep (wave15->wave0 is 3 iters apart).
__global__ __launch_bounds__(1024, 4) void stft_kernel(const float* __restrict__ mixed,
                                                       const float* __restrict__ transfer,
                                                       const float* __restrict__ gainp,
                                                       float* __restrict__ out) {
    __shared__ __align__(16) float2 buf[NW][256];
    __shared__ __align__(16) float2 spec[2][NW][257];
    __shared__ __align__(16) float  olab2[2][NW][264];
    __shared__ __align__(16) float  tails[4][264];

    const int tid  = threadIdx.x;
    const int bc   = blockIdx.x;
    const int b    = bc >> 6, c = bc & 63;
    const int g    = tid >> 6, lane = tid & 63;

    const float* src = mixed + ((size_t)(b * C_CH + c)) * T_PAD;
    float*       dst = out   + ((size_t)(b * C_CH + c)) * T_LEN;

    // ---- prefetch frame g (iteration 0)
    float2 pf0, pf1, pf2, pf3;
    {
        const float* fp = src + (size_t)g * STEP_;
        pf0 = *reinterpret_cast<const float2*>(fp + 2 * lane);
        pf1 = *reinterpret_cast<const float2*>(fp + 2 * (lane + 64));
        pf2 = *reinterpret_cast<const float2*>(fp + 2 * (lane + 128));
        pf3 = *reinterpret_cast<const float2*>(fp + 2 * (lane + 192));
    }

    // ---- per-lane constant twiddles (registers)
    const float TWO_PI = 6.2831853071795864f;
    float sn, cn;
    sincosf(TWO_PI * (float)lane / 256.0f, &sn, &cn);
    const float2 w1a = make_float2(cn, -sn), w2a = cmul(w1a, w1a), w3a = cmul(w2a, w1a);
    sincosf(TWO_PI * (float)(lane >> 2) / 64.0f, &sn, &cn);
    const float2 w1b = make_float2(cn, -sn), w2b = cmul(w1b, w1b), w3b = cmul(w2b, w1b);
    sincosf(TWO_PI * (float)(lane >> 4) / 16.0f, &sn, &cn);
    const float2 w1c = make_float2(cn, -sn), w2c = cmul(w1c, w1c), w3c = cmul(w2c, w1c);
    float2 wh[4];
#pragma unroll
    for (int qq = 0; qq < 4; ++qq) {
        sincosf(3.14159265358979f * (float)(lane + 64 * qq) / 256.0f, &sn, &cn);
        wh[qq] = make_float2(cn, -sn);
    }
#define HV(m) ((0.5f - 0.5f * cosf(TWO_PI * (float)(m) / 512.0f)) * (1.0f / 512.0f))
    const float h0 = HV(2 * lane),       h1 = HV(2 * lane + 1);
    const float h2 = HV(2 * lane + 128), h3 = HV(2 * lane + 129);
    const float h4 = HV(2 * lane + 256), h5 = HV(2 * lane + 257);
    const float h6 = HV(2 * lane + 384), h7 = HV(2 * lane + 385);
#undef HV

    // ---- loop-invariant LDS addresses (float2 index space)
    const int q2  = (lane & 3)  + ((lane >> 2) << 4);
    const int q3  = (lane & 15) + ((lane >> 4) << 6);
    const int swl = SW(lane);                    // SW(lane+64m) = swl+64m (verified)
    const int s1b = (4 * lane) ^ (lane & 12);    // SW(4*lane), contiguous run of 4
    const int sq2a = SW(q2);
    const int sq2b = SW(q2 + 4);
    const int sq2c = SW(q2 + 8);
    const int sq2d = SW(q2 + 12);
    const int sq3a = q3;                         // SW(q3)
    const int sq3b = (q3 + 16) ^ 4;              // SW(q3+16)
    const int sq3c = (q3 + 32) ^ 8;              // SW(q3+32)
    const int sq3d = (q3 + 48) ^ 12;             // SW(q3+48)
    const int mm0 = SW((256 - lane) & 255);      // Hermitian mirror reads
    const int mm1 = SW(192 - lane);
    const int mm2 = SW(128 - lane);
    const int mm3 = SW(64 - lane);

    // ---- scan: waves 0-3 full-lane (k=0..255), wave 4 lane 0 takes k=256.
    int sk = -1;
    if (g < 4) sk = (g << 6) | lane;
    else if (g == 4 && lane == 0) sk = 256;
    float  tk = 0.0f;
    float2 yc = make_float2(0.0f, 0.0f);
    if (sk >= 0) tk = transfer[c * K_ + sk];

    if (tid < 256) tails[3][tid] = 0.0f;   // store(0) wave 0 reads slot (0-1)&3 = 3
    const float gv = gainp[0];
    float2* bin = &buf[g][0];
    float2 sval0 = make_float2(0.f, 0.f), sval1 = make_float2(0.f, 0.f);
    BAR();

    for (int it = 0; it <= NIT + 1; ++it) {
        const int sp = it & 1;
        // ================= phase 1: forward frame it*NW+g =================
        if (it < NIT) {
            float2 z0 = pf0, z1 = pf1, z2 = pf2, z3 = pf3;
            if (it + 1 < NIT) {
                const float* fp = src + (size_t)((it + 1) * NW + g) * STEP_;
                pf0 = *reinterpret_cast<const float2*>(fp + 2 * lane);
                pf1 = *reinterpret_cast<const float2*>(fp + 2 * (lane + 64));
                pf2 = *reinterpret_cast<const float2*>(fp + 2 * (lane + 128));
                pf3 = *reinterpret_cast<const float2*>(fp + 2 * (lane + 192));
            }
            float2 o0, o1, o2, o3;
            bfly4<1>(z0, z1, z2, z3, o0, o1, o2, o3, w1a, w2a, w3a);
            {
                float2* bw = bin + s1b;
                *reinterpret_cast<float4*>(bw)     = make_float4(o0.x, o0.y, o1.x, o1.y);
                *reinterpret_cast<float4*>(bw + 2) = make_float4(o2.x, o2.y, o3.x, o3.y);
            }
            CFENCE();
            z0 = bin[swl]; z1 = bin[swl + 64]; z2 = bin[swl + 128]; z3 = bin[swl + 192];
            bfly4<1>(z0, z1, z2, z3, o0, o1, o2, o3, w1b, w2b, w3b);
            CFENCE();
            bin[sq2a] = o0; bin[sq2b] = o1; bin[sq2c] = o2; bin[sq2d] = o3;
            CFENCE();
            z0 = bin[swl]; z1 = bin[swl + 64]; z2 = bin[swl + 128]; z3 = bin[swl + 192];
            bfly4<1>(z0, z1, z2, z3, o0, o1, o2, o3, w1c, w2c, w3c);
            CFENCE();
            bin[sq3a] = o0; bin[sq3b] = o1; bin[sq3c] = o2; bin[sq3d] = o3;
            CFENCE();
            z0 = bin[swl]; z1 = bin[swl + 64]; z2 = bin[swl + 128]; z3 = bin[swl + 192];
            bfly4nt<1>(z0, z1, z2, z3, o0, o1, o2, o3);
            CFENCE();
            bin[swl] = o0; bin[swl + 64] = o1; bin[swl + 128] = o2; bin[swl + 192] = o3;
            CFENCE();
            {
                float2 v0 = bin[mm0], v1 = bin[mm1], v2 = bin[mm2], v3 = bin[mm3];
                float2 uu[4] = {o0, o1, o2, o3}, vv[4] = {v0, v1, v2, v3};
#pragma unroll
                for (int qq = 0; qq < 4; ++qq) {
                    int k = lane + 64 * qq;
                    float2 E = make_float2(0.5f * (uu[qq].x + vv[qq].x),  0.5f * (uu[qq].y - vv[qq].y));
                    float2 O = make_float2(0.5f * (uu[qq].y + vv[qq].y), -0.5f * (uu[qq].x - vv[qq].x));
                    spec[sp][g][k] = cadd(E, cmul(wh[qq], O));
                }
                if (lane == 0) spec[sp][g][256] = make_float2(o0.x - o0.y, 0.0f);
            }
        }
        BAR();   // B1 — the only barrier
        // ====== phase 2: scan(it) || inverse(it-1) || store(it-2) ======
        if (it < NIT && sk >= 0) {
            float2* s0 = &spec[sp][0][sk];
            float2 v[8]; float2 y = yc;
#pragma unroll
            for (int gg = 0; gg < 8; ++gg) v[gg] = s0[gg * 257];
#pragma unroll
            for (int gg = 0; gg < 8; ++gg) {
                y.x = (v[gg].x + y.x) * tk; y.y = (v[gg].y + y.y) * tk;
                s0[gg * 257] = y;
            }
#pragma unroll
            for (int gg = 0; gg < 8; ++gg) v[gg] = s0[(gg + 8) * 257];
#pragma unroll
            for (int gg = 0; gg < 8; ++gg) {
                y.x = (v[gg].x + y.x) * tk; y.y = (v[gg].y + y.y) * tk;
                s0[(gg + 8) * 257] = y;
            }
            yc = y;
        }
        float2 nv0, nv1;
        if (it >= 1 && it <= NIT) {
            const float2* specP = &spec[sp ^ 1][g][0];
            float2 o0, o1, o2, o3;
            {
                float2 iu[4], is_[4];
                iu[0] = specP[lane];       is_[0] = specP[256 - lane];
                iu[1] = specP[lane + 64];  is_[1] = specP[192 - lane];
                iu[2] = specP[lane + 128]; is_[2] = specP[128 - lane];
                iu[3] = specP[lane + 192]; is_[3] = specP[64 - lane];
                float2 zz[4];
#pragma unroll
                for (int qq = 0; qq < 4; ++qq) {
                    float2 A  = make_float2(iu[qq].x + is_[qq].x, iu[qq].y - is_[qq].y);
                    float2 D  = make_float2(iu[qq].x - is_[qq].x, iu[qq].y + is_[qq].y);
                    float2 Bv = cmulsg<-1>(wh[qq], D);
                    zz[qq] = make_float2(A.x - Bv.y, A.y + Bv.x);
                }
                bfly4<-1>(zz[0], zz[1], zz[2], zz[3], o0, o1, o2, o3, w1a, w2a, w3a);
            }
            {
                float2* bw = bin + s1b;
                *reinterpret_cast<float4*>(bw)     = make_float4(o0.x, o0.y, o1.x, o1.y);
                *reinterpret_cast<float4*>(bw + 2) = make_float4(o2.x, o2.y, o3.x, o3.y);
            }
            CFENCE();
            float2 z0 = bin[swl], z1 = bin[swl + 64], z2 = bin[swl + 128], z3 = bin[swl + 192];
            bfly4<-1>(z0, z1, z2, z3, o0, o1, o2, o3, w1b, w2b, w3b);
            CFENCE();
            bin[sq2a] = o0; bin[sq2b] = o1; bin[sq2c] = o2; bin[sq2d] = o3;
            CFENCE();
            z0 = bin[swl]; z1 = bin[swl + 64]; z2 = bin[swl + 128]; z3 = bin[swl + 192];
            bfly4<-1>(z0, z1, z2, z3, o0, o1, o2, o3, w1c, w2c, w3c);
            CFENCE();
            bin[sq3a] = o0; bin[sq3b] = o1; bin[sq3c] = o2; bin[sq3d] = o3;
            CFENCE();
            z0 = bin[swl]; z1 = bin[swl + 64]; z2 = bin[swl + 128]; z3 = bin[swl + 192];
            bfly4nt<-1>(z0, z1, z2, z3, o0, o1, o2, o3);
            // publish windowed second half for next iteration's store
            {
                float2 sh0 = make_float2(o2.x * h4, o2.y * h5);
                float2 sh1 = make_float2(o3.x * h6, o3.y * h7);
                float* wrow = (g == NW - 1) ? tails[(it - 1) & 3] : olab2[(it - 1) & 1][g + 1];
                *reinterpret_cast<float2*>(&wrow[2 * lane])       = sh0;
                *reinterpret_cast<float2*>(&wrow[2 * lane + 128]) = sh1;
            }
            nv0 = make_float2(o0.x * h0, o0.y * h1);
            nv1 = make_float2(o1.x * h2, o1.y * h3);
        } else {
            nv0 = make_float2(0.f, 0.f); nv1 = make_float2(0.f, 0.f);
        }
        if (it >= 2) {
            const int fs = (it - 2) * NW + g;
            const float* prow = (g == 0) ? tails[(it - 3) & 3] : olab2[(it - 2) & 1][g];
            float2 p0 = *reinterpret_cast<const float2*>(&prow[2 * lane]);
            float2 p1 = *reinterpret_cast<const float2*>(&prow[2 * lane + 128]);
            float2 r0 = make_float2(ftanh((sval0.x + p0.x) * gv),
                                    ftanh((sval0.y + p0.y) * gv));
            float2 r1 = make_float2(ftanh((sval1.x + p1.x) * gv),
                                    ftanh((sval1.y + p1.y) * gv));
            float* dp = dst + (size_t)fs * STEP_;
            *reinterpret_cast<float2*>(&dp[2 * lane])       = r0;
            *reinterpret_cast<float2*>(&dp[2 * lane + 128]) = r1;
        }
        sval0 = nv0; sval1 = nv1;
    }
}

extern "C" void kernel_launch(void* const* d_in, const int* in_sizes, int n_in,
                              void* d_out, int out_size, void* d_ws, size_t ws_size,
                              hipStream_t stream) {
    (void)in_sizes; (void)n_in; (void)out_size; (void)ws_size;
    const float* x        = (const float*)d_in[0];
    const float* mixer    = (const float*)d_in[1];
    const float* transfer = (const float*)d_in[2];
    const float* gain     = (const float*)d_in[3];
    float* out   = (float*)d_out;
    float* mixed = (float*)d_ws;   // (B, C, T_PAD) f32 = 67.4 MB

    dim3 gmix(T_PAD / 128, 4);
    mix_kernel<<<gmix, 512, 0, stream>>>(x, mixer, mixed);
    stft_kernel<<<256, 1024, 0, stream>>>(mixed, transfer, gain, out);
}

// Round 10
// 113.605 us; speedup vs baseline: 1.0165x; 1.0165x over previous
//
#include <hip/hip_runtime.h>
#include <math.h>

#define T_LEN  65536
#define T_PAD  65792      // T + STEP
#define C_CH   64
#define STEP_  256
#define K_     257        // WS/2 + 1
#define NW     16         // waves per block
#define NIT    16         // iterations (NW frames each)
#define SPITCH 17         // specT row pitch in float2 (16 frames + 1 pad)

// XOR-swizzle: fold float2-index bits[5:4] into bank bits[3:2].
#define SW(i) ((i) ^ (((i) >> 2) & 12))

#define CFENCE() asm volatile("" ::: "memory")
// barrier that does NOT drain vmcnt: prefetch loads stay in flight
#define BAR() do { asm volatile("s_waitcnt lgkmcnt(0)" ::: "memory"); \
                   __builtin_amdgcn_s_barrier(); \
                   asm volatile("" ::: "memory"); } while (0)

__device__ __forceinline__ float2 cadd(float2 a, float2 b) { return make_float2(a.x + b.x, a.y + b.y); }
__device__ __forceinline__ float2 csub(float2 a, float2 b) { return make_float2(a.x - b.x, a.y - b.y); }
__device__ __forceinline__ float2 cmul(float2 a, float2 b) {
    return make_float2(a.x * b.x - a.y * b.y, a.x * b.y + a.y * b.x);
}
template <int SGN>
__device__ __forceinline__ float2 cmulsg(float2 w, float2 t) {
    if (SGN > 0) return make_float2(w.x * t.x - w.y * t.y, w.x * t.y + w.y * t.x);
    else         return make_float2(w.x * t.x + w.y * t.y, w.x * t.y - w.y * t.x);
}
template <int SGN>
__device__ __forceinline__ void bfly4(float2 z0, float2 z1, float2 z2, float2 z3,
                                      float2& o0, float2& o1, float2& o2, float2& o3,
                                      float2 w1, float2 w2, float2 w3) {
    float2 apc = cadd(z0, z2), amc = csub(z0, z2);
    float2 bpd = cadd(z1, z3), bmd = csub(z1, z3);
    float2 jb  = make_float2(-bmd.y, bmd.x);
    float2 t1, t3;
    if (SGN > 0) { t1 = csub(amc, jb); t3 = cadd(amc, jb); }
    else         { t1 = cadd(amc, jb); t3 = csub(amc, jb); }
    o0 = cadd(apc, bpd);
    o1 = cmulsg<SGN>(w1, t1);
    o2 = cmulsg<SGN>(w2, csub(apc, bpd));
    o3 = cmulsg<SGN>(w3, t3);
}
template <int SGN>
__device__ __forceinline__ void bfly4nt(float2 z0, float2 z1, float2 z2, float2 z3,
                                        float2& o0, float2& o1, float2& o2, float2& o3) {
    float2 apc = cadd(z0, z2), amc = csub(z0, z2);
    float2 bpd = cadd(z1, z3), bmd = csub(z1, z3);
    float2 jb  = make_float2(-bmd.y, bmd.x);
    o0 = cadd(apc, bpd);
    o2 = csub(apc, bpd);
    if (SGN > 0) { o1 = csub(amc, jb); o3 = cadd(amc, jb); }
    else         { o1 = cadd(amc, jb); o3 = csub(amc, jb); }
}

__device__ __forceinline__ float ftanh(float x) {
    float e = __expf(2.0f * x);
    return 1.0f - 2.0f * __builtin_amdgcn_rcpf(e + 1.0f);
}

// ---------------- kernel 1: channel mix + zero pad -------------------------
__global__ __launch_bounds__(512, 1) void mix_kernel(const float* __restrict__ x,
                                                     const float* __restrict__ mixer,
                                                     float* __restrict__ mixed) {
    __shared__ __align__(16) float xt[64][128];
    __shared__ __align__(16) float mx[64][64];
    int tid = threadIdx.x;
    int b   = blockIdx.y;
    int t0  = blockIdx.x * 128;

    if (t0 >= T_LEN) {   // zero-pad region [T, T_PAD)
        for (int f = tid; f < 8192; f += 512) {
            int d = f >> 7, tt = f & 127;
            mixed[((size_t)(b * C_CH + d)) * T_PAD + t0 + tt] = 0.0f;
        }
        return;
    }
    for (int f = tid; f < 4096; f += 512) reinterpret_cast<float*>(mx)[f] = mixer[f];
    for (int f4 = tid; f4 < 2048; f4 += 512) {
        int cc = f4 >> 5, tt4 = f4 & 31;
        *reinterpret_cast<float4*>(&xt[cc][tt4 * 4]) =
            *reinterpret_cast<const float4*>(&x[((size_t)(b * C_CH + cc)) * T_LEN + t0 + tt4 * 4]);
    }
    __syncthreads();

    int tp = tid & 63, grp = tid >> 6;
    int dbase = grp * 8;
    float2 acc[8];
#pragma unroll
    for (int i = 0; i < 8; ++i) acc[i] = make_float2(0.0f, 0.0f);
    for (int cc = 0; cc < 64; ++cc) {
        float2 xv = *reinterpret_cast<const float2*>(&xt[cc][2 * tp]);
        float4 m0 = *reinterpret_cast<const float4*>(&mx[cc][dbase + 0]);
        float4 m1 = *reinterpret_cast<const float4*>(&mx[cc][dbase + 4]);
        acc[0].x = fmaf(xv.x, m0.x, acc[0].x); acc[0].y = fmaf(xv.y, m0.x, acc[0].y);
        acc[1].x = fmaf(xv.x, m0.y, acc[1].x); acc[1].y = fmaf(xv.y, m0.y, acc[1].y);
        acc[2].x = fmaf(xv.x, m0.z, acc[2].x); acc[2].y = fmaf(xv.y, m0.z, acc[2].y);
        acc[3].x = fmaf(xv.x, m0.w, acc[3].x); acc[3].y = fmaf(xv.y, m0.w, acc[3].y);
        acc[4].x = fmaf(xv.x, m1.x, acc[4].x); acc[4].y = fmaf(xv.y, m1.x, acc[4].y);
        acc[5].x = fmaf(xv.x, m1.y, acc[5].x); acc[5].y = fmaf(xv.y, m1.y, acc[5].y);
        acc[6].x = fmaf(xv.x, m1.z, acc[6].x); acc[6].y = fmaf(xv.y, m1.z, acc[6].y);
        acc[7].x = fmaf(xv.x, m1.w, acc[7].x); acc[7].y = fmaf(xv.y, m1.w, acc[7].y);
    }
#pragma unroll
    for (int i = 0; i < 8; ++i)
        *reinterpret_cast<float2*>(&mixed[((size_t)(b * C_CH + dbase + i)) * T_PAD + t0 + 2 * tp]) = acc[i];
}

// -------- kernel 2: fused STFT -> scan -> iSTFT -> window -> OLA -> tanh ---
// r8 schedule with BIN-MAJOR spec layout: specT[k*17 + g]. The scan walks
// unit-stride frames (ds_read2/write2_b64); all other patterns stay
// bank-spread ((lane +/- g) % 16).
__global__ __launch_bounds__(1024, 4) void stft_kernel(const float* __restrict__ mixed,
                                                       const float* __restrict__ transfer,
                                                       const float* __restrict__ gainp,
                                                       float* __restrict__ out) {
    __shared__ __align__(16) float2 buf[NW][256];
    __shared__ __align__(16) float2 specT[2][K_ * SPITCH];   // bin-major, pitch 17
    __shared__ __align__(16) float  olab[NW][264];
    __shared__ __align__(16) float  tails[2][264];

    const int tid  = threadIdx.x;
    const int bc   = blockIdx.x;
    const int b    = bc >> 6, c = bc & 63;
    const int g    = tid >> 6, lane = tid & 63;

    const float* src = mixed + ((size_t)(b * C_CH + c)) * T_PAD;
    float*       dst = out   + ((size_t)(b * C_CH + c)) * T_LEN;

    // ---- prefetch frame g (iteration 0)
    float2 pf0, pf1, pf2, pf3;
    {
        const float* fp = src + (size_t)g * STEP_;
        pf0 = *reinterpret_cast<const float2*>(fp + 2 * lane);
        pf1 = *reinterpret_cast<const float2*>(fp + 2 * (lane + 64));
        pf2 = *reinterpret_cast<const float2*>(fp + 2 * (lane + 128));
        pf3 = *reinterpret_cast<const float2*>(fp + 2 * (lane + 192));
    }

    // ---- per-lane constant twiddles (registers)
    const float TWO_PI = 6.2831853071795864f;
    float sn, cn;
    sincosf(TWO_PI * (float)lane / 256.0f, &sn, &cn);
    const float2 w1a = make_float2(cn, -sn), w2a = cmul(w1a, w1a), w3a = cmul(w2a, w1a);
    sincosf(TWO_PI * (float)(lane >> 2) / 64.0f, &sn, &cn);
    const float2 w1b = make_float2(cn, -sn), w2b = cmul(w1b, w1b), w3b = cmul(w2b, w1b);
    sincosf(TWO_PI * (float)(lane >> 4) / 16.0f, &sn, &cn);
    const float2 w1c = make_float2(cn, -sn), w2c = cmul(w1c, w1c), w3c = cmul(w2c, w1c);
    float2 wh[4];
#pragma unroll
    for (int qq = 0; qq < 4; ++qq) {
        sincosf(3.14159265358979f * (float)(lane + 64 * qq) / 256.0f, &sn, &cn);
        wh[qq] = make_float2(cn, -sn);
    }
#define HV(m) ((0.5f - 0.5f * cosf(TWO_PI * (float)(m) / 512.0f)) * (1.0f / 512.0f))
    const float h0 = HV(2 * lane),       h1 = HV(2 * lane + 1);
    const float h2 = HV(2 * lane + 128), h3 = HV(2 * lane + 129);
    const float h4 = HV(2 * lane + 256), h5 = HV(2 * lane + 257);
    const float h6 = HV(2 * lane + 384), h7 = HV(2 * lane + 385);
#undef HV

    // ---- loop-invariant LDS addresses (float2 index space)
    const int q2  = (lane & 3)  + ((lane >> 2) << 4);
    const int q3  = (lane & 15) + ((lane >> 4) << 6);
    const int swl = SW(lane);                    // SW(lane+64m) = swl+64m (verified)
    const int s1b = (4 * lane) ^ (lane & 12);    // SW(4*lane), contiguous run of 4
    const int sq2a = SW(q2);
    const int sq2b = SW(q2 + 4);
    const int sq2c = SW(q2 + 8);
    const int sq2d = SW(q2 + 12);
    const int sq3a = q3;                         // SW(q3)
    const int sq3b = (q3 + 16) ^ 4;              // SW(q3+16)
    const int sq3c = (q3 + 32) ^ 8;              // SW(q3+32)
    const int sq3d = (q3 + 48) ^ 12;             // SW(q3+48)
    const int mm0 = SW((256 - lane) & 255);      // Hermitian mirror reads (in buf)
    const int mm1 = SW(192 - lane);
    const int mm2 = SW(128 - lane);
    const int mm3 = SW(64 - lane);
    // specT offsets: write/read bins k = lane + 64q at column g
    const int spw  = lane * SPITCH + g;          // + 64*SPITCH*q
    const int spm  = 256 * SPITCH + g - lane * SPITCH;  // mirror (256-lane)*17+g, -64*SPITCH*q

    // ---- scan: waves 0-3 full-lane (k=0..255), wave 4 lane 0 takes k=256.
    int sk = -1;
    if (g < 4) sk = (g << 6) | lane;
    else if (g == 4 && lane == 0) sk = 256;
    float  tk = 0.0f;
    float2 yc = make_float2(0.0f, 0.0f);
    if (sk >= 0) tk = transfer[c * K_ + sk];

    if (tid < 256) tails[0][tid] = 0.0f;
    const float gv = gainp[0];
    float2* bin = &buf[g][0];
    BAR();

    for (int it = 0; it <= NIT; ++it) {
        const int sp = it & 1;
        // ================= forward: frame it*NW+g =================
        if (it < NIT) {
            const int f = it * NW + g;
            float2 z0 = pf0, z1 = pf1, z2 = pf2, z3 = pf3;
            if (it + 1 < NIT) {
                const float* fp = src + (size_t)(f + NW) * STEP_;
                pf0 = *reinterpret_cast<const float2*>(fp + 2 * lane);
                pf1 = *reinterpret_cast<const float2*>(fp + 2 * (lane + 64));
                pf2 = *reinterpret_cast<const float2*>(fp + 2 * (lane + 128));
                pf3 = *reinterpret_cast<const float2*>(fp + 2 * (lane + 192));
            }
            float2 o0, o1, o2, o3;
            bfly4<1>(z0, z1, z2, z3, o0, o1, o2, o3, w1a, w2a, w3a);
            {
                float2* bw = bin + s1b;
                *reinterpret_cast<float4*>(bw)     = make_float4(o0.x, o0.y, o1.x, o1.y);
                *reinterpret_cast<float4*>(bw + 2) = make_float4(o2.x, o2.y, o3.x, o3.y);
            }
            CFENCE();
            z0 = bin[swl]; z1 = bin[swl + 64]; z2 = bin[swl + 128]; z3 = bin[swl + 192];
            bfly4<1>(z0, z1, z2, z3, o0, o1, o2, o3, w1b, w2b, w3b);
            CFENCE();
            bin[sq2a] = o0; bin[sq2b] = o1; bin[sq2c] = o2; bin[sq2d] = o3;
            CFENCE();
            z0 = bin[swl]; z1 = bin[swl + 64]; z2 = bin[swl + 128]; z3 = bin[swl + 192];
            bfly4<1>(z0, z1, z2, z3, o0, o1, o2, o3, w1c, w2c, w3c);
            CFENCE();
            bin[sq3a] = o0; bin[sq3b] = o1; bin[sq3c] = o2; bin[sq3d] = o3;
            CFENCE();
            z0 = bin[swl]; z1 = bin[swl + 64]; z2 = bin[swl + 128]; z3 = bin[swl + 192];
            bfly4nt<1>(z0, z1, z2, z3, o0, o1, o2, o3);
            CFENCE();
            bin[swl] = o0; bin[swl + 64] = o1; bin[swl + 128] = o2; bin[swl + 192] = o3;
            CFENCE();
            // Hermitian: u from regs (o_q = X[lane+64q]), v mirrors from LDS
            {
                float2 v0 = bin[mm0], v1 = bin[mm1], v2 = bin[mm2], v3 = bin[mm3];
                float2 uu[4] = {o0, o1, o2, o3}, vv[4] = {v0, v1, v2, v3};
                float2* st = &specT[sp][0];
#pragma unroll
                for (int qq = 0; qq < 4; ++qq) {
                    float2 E = make_float2(0.5f * (uu[qq].x + vv[qq].x),  0.5f * (uu[qq].y - vv[qq].y));
                    float2 O = make_float2(0.5f * (uu[qq].y + vv[qq].y), -0.5f * (uu[qq].x - vv[qq].x));
                    st[spw + 64 * SPITCH * qq] = cadd(E, cmul(wh[qq], O));
                }
                if (lane == 0) st[256 * SPITCH + g] = make_float2(o0.x - o0.y, 0.0f);
            }
        }
        BAR();   // B1: specT[sp] complete
        // ====== scan(it) on waves 0-4 (unit-stride frames) || inverse(it-1) ======
        if (it < NIT && sk >= 0) {
            float2* s0 = &specT[sp][sk * SPITCH];
            float2 v[8]; float2 y = yc;
#pragma unroll
            for (int gg = 0; gg < 8; ++gg) v[gg] = s0[gg];
#pragma unroll
            for (int gg = 0; gg < 8; ++gg) {
                y.x = (v[gg].x + y.x) * tk; y.y = (v[gg].y + y.y) * tk;
                s0[gg] = y;
            }
#pragma unroll
            for (int gg = 0; gg < 8; ++gg) v[gg] = s0[gg + 8];
#pragma unroll
            for (int gg = 0; gg < 8; ++gg) {
                y.x = (v[gg].x + y.x) * tk; y.y = (v[gg].y + y.y) * tk;
                s0[gg + 8] = y;
            }
            yc = y;
        }
        // ============ inverse + OLA for frame (it-1)*NW+g ============
        if (it > 0) {
            const int fb = (it - 1) * NW + g;
            const float2* st = &specT[sp ^ 1][0];
            float2 o0, o1, o2, o3;
            {
                float2 iu[4], is_[4];
#pragma unroll
                for (int qq = 0; qq < 4; ++qq) {
                    iu[qq]  = st[spw + 64 * SPITCH * qq];
                    is_[qq] = st[spm - 64 * SPITCH * qq];
                }
                float2 zz[4];
#pragma unroll
                for (int qq = 0; qq < 4; ++qq) {
                    float2 A  = make_float2(iu[qq].x + is_[qq].x, iu[qq].y - is_[qq].y);
                    float2 D  = make_float2(iu[qq].x - is_[qq].x, iu[qq].y + is_[qq].y);
                    float2 Bv = cmulsg<-1>(wh[qq], D);
                    zz[qq] = make_float2(A.x - Bv.y, A.y + Bv.x);
                }
                bfly4<-1>(zz[0], zz[1], zz[2], zz[3], o0, o1, o2, o3, w1a, w2a, w3a);
            }
            {
                float2* bw = bin + s1b;
                *reinterpret_cast<float4*>(bw)     = make_float4(o0.x, o0.y, o1.x, o1.y);
                *reinterpret_cast<float4*>(bw + 2) = make_float4(o2.x, o2.y, o3.x, o3.y);
            }
            CFENCE();
            float2 z0 = bin[swl], z1 = bin[swl + 64], z2 = bin[swl + 128], z3 = bin[swl + 192];
            bfly4<-1>(z0, z1, z2, z3, o0, o1, o2, o3, w1b, w2b, w3b);
            CFENCE();
            bin[sq2a] = o0; bin[sq2b] = o1; bin[sq2c] = o2; bin[sq2d] = o3;
            CFENCE();
            z0 = bin[swl]; z1 = bin[swl + 64]; z2 = bin[swl + 128]; z3 = bin[swl + 192];
            bfly4<-1>(z0, z1, z2, z3, o0, o1, o2, o3, w1c, w2c, w3c);
            CFENCE();
            bin[sq3a] = o0; bin[sq3b] = o1; bin[sq3c] = o2; bin[sq3d] = o3;
            CFENCE();
            z0 = bin[swl]; z1 = bin[swl + 64]; z2 = bin[swl + 128]; z3 = bin[swl + 192];
            bfly4nt<-1>(z0, z1, z2, z3, o0, o1, o2, o3);
            // publish windowed second half for neighbor / next-iter tail
            {
                float2 sh0 = make_float2(o2.x * h4, o2.y * h5);
                float2 sh1 = make_float2(o3.x * h6, o3.y * h7);
                float* wrow = (g == NW - 1) ? tails[it & 1] : olab[g + 1];
                *reinterpret_cast<float2*>(&wrow[2 * lane])       = sh0;
                *reinterpret_cast<float2*>(&wrow[2 * lane + 128]) = sh1;
            }
            BAR();   // B2: neighbor halves visible, scan done
            {
                const float* prow = (g == 0) ? tails[(it - 1) & 1] : olab[g];
                float2 p0 = *reinterpret_cast<const float2*>(&prow[2 * lane]);
                float2 p1 = *reinterpret_cast<const float2*>(&prow[2 * lane + 128]);
                float2 r0 = make_float2(ftanh((o0.x * h0 + p0.x) * gv),
                                        ftanh((o0.y * h1 + p0.y) * gv));
                float2 r1 = make_float2(ftanh((o1.x * h2 + p1.x) * gv),
                                        ftanh((o1.y * h3 + p1.y) * gv));
                float* dp = dst + (size_t)fb * STEP_;
                *reinterpret_cast<float2*>(&dp[2 * lane])       = r0;
                *reinterpret_cast<float2*>(&dp[2 * lane + 128]) = r1;
            }
        }
    }
}

extern "C" void kernel_launch(void* const* d_in, const int* in_sizes, int n_in,
                              void* d_out, int out_size, void* d_ws, size_t ws_size,
                              hipStream_t stream) {
    (void)in_sizes; (void)n_in; (void)out_size; (void)ws_size;
    const float* x        = (const float*)d_in[0];
    const float* mixer    = (const float*)d_in[1];
    const float* transfer = (const float*)d_in[2];
    const float* gain     = (const float*)d_in[3];
    float* out   = (float*)d_out;
    float* mixed = (float*)d_ws;   // (B, C, T_PAD) f32 = 67.4 MB

    dim3 gmix(T_PAD / 128, 4);
    mix_kernel<<<gmix, 512, 0, stream>>>(x, mixer, mixed);
    stft_kernel<<<256, 1024, 0, stream>>>(mixed, transfer, gain, out);
}